// Round 4
// baseline (419.972 us; speedup 1.0000x reference)
//
#include <hip/hip_runtime.h>

#define SQ   2048
#define DD   64
#define BK   64
#define BQ   128
#define LDW  72
#define NBH  32

typedef _Float16 f16x8 __attribute__((ext_vector_type(8)));
typedef _Float16 f16x4 __attribute__((ext_vector_type(4)));
typedef float    f32x4 __attribute__((ext_vector_type(4)));

// scale = 1/sqrt(2048) (dk = key len!) folded with log2(e): exp(x*s) = 2^(x*s*log2e)
#define SCALE_LOG2E ((float)(0.02209708691207961 * 1.4426950408889634))
#define MASKED_VAL  (-1e10f * SCALE_LOG2E)

template<bool SPLIT>
__global__ __launch_bounds__(256, 4)
void attn_fa(const float* __restrict__ Qg,
             const float* __restrict__ Kg,
             const float* __restrict__ Vg,
             const unsigned char* __restrict__ maskg,
             float* __restrict__ Og,
             float* __restrict__ wsAcc,
             float* __restrict__ wsL)
{
    __shared__ _Float16 Kl[2][BK * LDW];   // [buf][key][d]
    __shared__ _Float16 Vt[2][DD * LDW];   // [buf][d][key'] (frag-major permuted)

    const int tid  = threadIdx.x;
    const int lane = tid & 63;
    const int w    = tid >> 6;
    const int quad = lane >> 4;
    const int l16  = lane & 15;

    // XCD swizzle: low 5 bits = bh -> all q-tiles (and kv-halves) of one head on one XCD
    const int n    = blockIdx.x;
    const int bh   = (n & 7) + 8 * ((n >> 3) & 3);
    const int half = SPLIT ? ((n >> 5) & 1) : 0;
    const int qtile = SPLIT ? (n >> 6) : (n >> 5);
    const int qBase = qtile * BQ;
    const int kt0  = SPLIT ? half * 16 : 0;
    const int KTN  = SPLIT ? 16 : 32;

    // ---- Q fragments, pre-scaled by scale*log2e ----
    f16x8 qf[2][2];
#pragma unroll
    for (int qg = 0; qg < 2; ++qg) {
        const float* qrow = Qg + ((size_t)bh * SQ + qBase + w * 32 + qg * 16 + l16) * DD;
#pragma unroll
        for (int h = 0; h < 2; ++h) {
            float4 a = *(const float4*)(qrow + h * 32 + quad * 8);
            float4 b = *(const float4*)(qrow + h * 32 + quad * 8 + 4);
            qf[qg][h][0] = (_Float16)(a.x * SCALE_LOG2E); qf[qg][h][1] = (_Float16)(a.y * SCALE_LOG2E);
            qf[qg][h][2] = (_Float16)(a.z * SCALE_LOG2E); qf[qg][h][3] = (_Float16)(a.w * SCALE_LOG2E);
            qf[qg][h][4] = (_Float16)(b.x * SCALE_LOG2E); qf[qg][h][5] = (_Float16)(b.y * SCALE_LOG2E);
            qf[qg][h][6] = (_Float16)(b.z * SCALE_LOG2E); qf[qg][h][7] = (_Float16)(b.w * SCALE_LOG2E);
        }
    }

    f32x4 acc[2][4];
#pragma unroll
    for (int qg = 0; qg < 2; ++qg)
#pragma unroll
        for (int d = 0; d < 4; ++d) acc[qg][d] = (f32x4){0.f, 0.f, 0.f, 0.f};
    float lsum[2] = {0.f, 0.f};

    // staging maps
    const int sr  = tid >> 2;             // K row 0..63
    const int sc4 = (tid & 3) * 16;       // K col chunk
    const int vq  = tid & 15;             // V key-quad (keys vq*4..vq*4+3)
    const int vdb = (tid >> 4) * 4;       // V d block
    const int ctw = vq >> 2, qdw = vq & 3;
    const int keyp = (ctw >> 1) * 32 + qdw * 8 + (ctw & 1) * 4;  // permuted col'

    const float* Kbase = Kg + (size_t)bh * SQ * DD;
    const float* Vbase = Vg + (size_t)bh * SQ * DD;
    const unsigned char* mbase = maskg + (size_t)(qBase + (tid >> 1)) * SQ + (tid & 1) * 32;

    // ---- prologue: stage tile kt0 ----
    {
        const float* ks = Kbase + (size_t)(kt0 * BK + sr) * DD + sc4;
        float4 k0v = *(const float4*)(ks + 0), k1v = *(const float4*)(ks + 4);
        float4 k2v = *(const float4*)(ks + 8), k3v = *(const float4*)(ks + 12);
        const float* vb = Vbase + (size_t)(kt0 * BK + vq * 4) * DD + vdb;
        float4 v0 = *(const float4*)(vb);          float4 v1 = *(const float4*)(vb + DD);
        float4 v2 = *(const float4*)(vb + 2 * DD); float4 v3 = *(const float4*)(vb + 3 * DD);
        f16x8 y0, y1;
        y0[0]=(_Float16)k0v.x; y0[1]=(_Float16)k0v.y; y0[2]=(_Float16)k0v.z; y0[3]=(_Float16)k0v.w;
        y0[4]=(_Float16)k1v.x; y0[5]=(_Float16)k1v.y; y0[6]=(_Float16)k1v.z; y0[7]=(_Float16)k1v.w;
        y1[0]=(_Float16)k2v.x; y1[1]=(_Float16)k2v.y; y1[2]=(_Float16)k2v.z; y1[3]=(_Float16)k2v.w;
        y1[4]=(_Float16)k3v.x; y1[5]=(_Float16)k3v.y; y1[6]=(_Float16)k3v.z; y1[7]=(_Float16)k3v.w;
        *(f16x8*)&Kl[0][sr * LDW + sc4]     = y0;
        *(f16x8*)&Kl[0][sr * LDW + sc4 + 8] = y1;
        f16x4 t0 = {(_Float16)v0.x,(_Float16)v1.x,(_Float16)v2.x,(_Float16)v3.x};
        f16x4 t1 = {(_Float16)v0.y,(_Float16)v1.y,(_Float16)v2.y,(_Float16)v3.y};
        f16x4 t2 = {(_Float16)v0.z,(_Float16)v1.z,(_Float16)v2.z,(_Float16)v3.z};
        f16x4 t3 = {(_Float16)v0.w,(_Float16)v1.w,(_Float16)v2.w,(_Float16)v3.w};
        *(f16x4*)&Vt[0][(vdb + 0) * LDW + keyp] = t0;
        *(f16x4*)&Vt[0][(vdb + 1) * LDW + keyp] = t1;
        *(f16x4*)&Vt[0][(vdb + 2) * LDW + keyp] = t2;
        *(f16x4*)&Vt[0][(vdb + 3) * LDW + keyp] = t3;
    }
    uint4 ma = *(const uint4*)(mbase + kt0 * BK), mb = *(const uint4*)(mbase + kt0 * BK + 16);
    int tm = __syncthreads_or((int)(ma.x | ma.y | ma.z | ma.w | mb.x | mb.y | mb.z | mb.w));

#pragma unroll 2
    for (int idx = 0; idx < KTN; ++idx) {
        const int kt  = kt0 + idx;
        const int cur = idx & 1;
        const bool more = (idx + 1 < KTN);

        // ---- register prefetch of next tile ----
        float4 kx[4], vx[4]; uint4 ma2 = {0,0,0,0}, mb2 = {0,0,0,0};
        if (more) {
            const int k0n = (kt + 1) * BK;
            const float* ks = Kbase + (size_t)(k0n + sr) * DD + sc4;
            kx[0] = *(const float4*)(ks + 0);  kx[1] = *(const float4*)(ks + 4);
            kx[2] = *(const float4*)(ks + 8);  kx[3] = *(const float4*)(ks + 12);
            const float* vb = Vbase + (size_t)(k0n + vq * 4) * DD + vdb;
            vx[0] = *(const float4*)(vb);           vx[1] = *(const float4*)(vb + DD);
            vx[2] = *(const float4*)(vb + 2 * DD);  vx[3] = *(const float4*)(vb + 3 * DD);
            ma2 = *(const uint4*)(mbase + k0n);
            mb2 = *(const uint4*)(mbase + k0n + 16);
        }

        // ---- S^T = K*Q^T ----
        f32x4 sA[4], sB[4];
#pragma unroll
        for (int ct = 0; ct < 4; ++ct) {
            f16x8 kf0 = *(const f16x8*)&Kl[cur][(ct * 16 + l16) * LDW + quad * 8];
            f16x8 kf1 = *(const f16x8*)&Kl[cur][(ct * 16 + l16) * LDW + 32 + quad * 8];
            f32x4 c0 = (f32x4){0.f, 0.f, 0.f, 0.f};
            c0 = __builtin_amdgcn_mfma_f32_16x16x32_f16(kf0, qf[0][0], c0, 0, 0, 0);
            c0 = __builtin_amdgcn_mfma_f32_16x16x32_f16(kf1, qf[0][1], c0, 0, 0, 0);
            sA[ct] = c0;
            f32x4 c1 = (f32x4){0.f, 0.f, 0.f, 0.f};
            c1 = __builtin_amdgcn_mfma_f32_16x16x32_f16(kf0, qf[1][0], c1, 0, 0, 0);
            c1 = __builtin_amdgcn_mfma_f32_16x16x32_f16(kf1, qf[1][1], c1, 0, 0, 0);
            sB[ct] = c1;
        }

        // ---- mask (rare slow path; logits already in log2 domain) ----
        if (tm) {
#pragma unroll
            for (int qg = 0; qg < 2; ++qg) {
                const int qgq = qBase + w * 32 + qg * 16 + l16;
#pragma unroll
                for (int ct = 0; ct < 4; ++ct)
#pragma unroll
                    for (int r = 0; r < 4; ++r) {
                        const int kg = kt * BK + ct * 16 + quad * 4 + r;
                        if (maskg[(size_t)qgq * SQ + kg]) {
                            if (qg == 0) sA[ct][r] = MASKED_VAL; else sB[ct][r] = MASKED_VAL;
                        }
                    }
            }
        }

        // ---- softmax numerators: per-lane, no max (|logit| bounded), raw v_exp ----
        f16x8 pA[2], pB[2];   // [kb]: 8 keys = ct(2kb) r0..3 | ct(2kb+1) r0..3
        float ls0 = 0.f, ls1 = 0.f;
#pragma unroll
        for (int kb = 0; kb < 2; ++kb)
#pragma unroll
            for (int j = 0; j < 8; ++j) {
                const int ct = kb * 2 + (j >> 2), r = j & 3;
                const float ea = __builtin_amdgcn_exp2f(sA[ct][r]);
                const float eb = __builtin_amdgcn_exp2f(sB[ct][r]);
                ls0 += ea; ls1 += eb;
                pA[kb][j] = (_Float16)ea;
                pB[kb][j] = (_Float16)eb;
            }
        lsum[0] += ls0; lsum[1] += ls1;

        // ---- P*V with 16x16x32: B-frag = one contiguous f16x8 from permuted Vt ----
#pragma unroll
        for (int dt = 0; dt < 4; ++dt)
#pragma unroll
            for (int kb = 0; kb < 2; ++kb) {
                f16x8 vv = *(const f16x8*)&Vt[cur][(dt * 16 + l16) * LDW + kb * 32 + quad * 8];
                acc[0][dt] = __builtin_amdgcn_mfma_f32_16x16x32_f16(pA[kb], vv, acc[0][dt], 0, 0, 0);
                acc[1][dt] = __builtin_amdgcn_mfma_f32_16x16x32_f16(pB[kb], vv, acc[1][dt], 0, 0, 0);
            }

        // ---- stage prefetched tile ----
        if (more) {
            f16x8 y0, y1;
            y0[0]=(_Float16)kx[0].x; y0[1]=(_Float16)kx[0].y; y0[2]=(_Float16)kx[0].z; y0[3]=(_Float16)kx[0].w;
            y0[4]=(_Float16)kx[1].x; y0[5]=(_Float16)kx[1].y; y0[6]=(_Float16)kx[1].z; y0[7]=(_Float16)kx[1].w;
            y1[0]=(_Float16)kx[2].x; y1[1]=(_Float16)kx[2].y; y1[2]=(_Float16)kx[2].z; y1[3]=(_Float16)kx[2].w;
            y1[4]=(_Float16)kx[3].x; y1[5]=(_Float16)kx[3].y; y1[6]=(_Float16)kx[3].z; y1[7]=(_Float16)kx[3].w;
            *(f16x8*)&Kl[cur ^ 1][sr * LDW + sc4]     = y0;
            *(f16x8*)&Kl[cur ^ 1][sr * LDW + sc4 + 8] = y1;
            f16x4 t0 = {(_Float16)vx[0].x,(_Float16)vx[1].x,(_Float16)vx[2].x,(_Float16)vx[3].x};
            f16x4 t1 = {(_Float16)vx[0].y,(_Float16)vx[1].y,(_Float16)vx[2].y,(_Float16)vx[3].y};
            f16x4 t2 = {(_Float16)vx[0].z,(_Float16)vx[1].z,(_Float16)vx[2].z,(_Float16)vx[3].z};
            f16x4 t3 = {(_Float16)vx[0].w,(_Float16)vx[1].w,(_Float16)vx[2].w,(_Float16)vx[3].w};
            *(f16x4*)&Vt[cur ^ 1][(vdb + 0) * LDW + keyp] = t0;
            *(f16x4*)&Vt[cur ^ 1][(vdb + 1) * LDW + keyp] = t1;
            *(f16x4*)&Vt[cur ^ 1][(vdb + 2) * LDW + keyp] = t2;
            *(f16x4*)&Vt[cur ^ 1][(vdb + 3) * LDW + keyp] = t3;
        }
        tm = __syncthreads_or((int)(ma2.x | ma2.y | ma2.z | ma2.w | mb2.x | mb2.y | mb2.z | mb2.w));
    }

    // ---- epilogue ----
#pragma unroll
    for (int qg = 0; qg < 2; ++qg) {
        float l = lsum[qg];
        l += __shfl_xor(l, 16);
        l += __shfl_xor(l, 32);
        if (SPLIT) {
            float* ob = wsAcc + (((size_t)half * NBH + bh) * SQ + qBase + w * 32 + qg * 16) * DD;
#pragma unroll
            for (int r = 0; r < 4; ++r) {
                const int qr = quad * 4 + r;
#pragma unroll
                for (int dt = 0; dt < 4; ++dt)
                    ob[qr * DD + dt * 16 + l16] = acc[qg][dt][r];
            }
            if (quad == 0)
                wsL[((size_t)half * NBH + bh) * SQ + qBase + w * 32 + qg * 16 + l16] = l;
        } else {
            float lrow[4];
#pragma unroll
            for (int r = 0; r < 4; ++r) lrow[r] = __shfl(l, quad * 4 + r);
            float* ob = Og + ((size_t)bh * SQ + qBase + w * 32 + qg * 16) * DD;
#pragma unroll
            for (int r = 0; r < 4; ++r) {
                const float inv = 1.0f / lrow[r];
                const int qr = quad * 4 + r;
#pragma unroll
                for (int dt = 0; dt < 4; ++dt)
                    ob[qr * DD + dt * 16 + l16] = acc[qg][dt][r] * inv;
            }
        }
    }
}

__global__ __launch_bounds__(256)
void attn_combine(const float* __restrict__ wsAcc,
                  const float* __restrict__ wsL,
                  float* __restrict__ Og)
{
    const int G   = blockIdx.x * 256 + threadIdx.x;   // 0 .. 32*2048*16-1
    const int row = G >> 4;                            // bh*SQ + q
    const int c   = G & 15;
    const size_t HALF4 = (size_t)NBH * SQ * (DD / 4);
    float4 a0 = ((const float4*)wsAcc)[(size_t)row * 16 + c];
    float4 a1 = ((const float4*)wsAcc)[HALF4 + (size_t)row * 16 + c];
    const float inv = 1.0f / (wsL[row] + wsL[(size_t)NBH * SQ + row]);
    float4 o;
    o.x = (a0.x + a1.x) * inv;
    o.y = (a0.y + a1.y) * inv;
    o.z = (a0.z + a1.z) * inv;
    o.w = (a0.w + a1.w) * inv;
    ((float4*)Og)[(size_t)row * 16 + c] = o;
}

extern "C" void kernel_launch(void* const* d_in, const int* in_sizes, int n_in,
                              void* d_out, int out_size, void* d_ws, size_t ws_size,
                              hipStream_t stream) {
    const float* Q = (const float*)d_in[0];
    const float* K = (const float*)d_in[1];
    const float* V = (const float*)d_in[2];
    const unsigned char* mask = (const unsigned char*)d_in[3];
    float* Out = (float*)d_out;

    const size_t accFloats = (size_t)2 * NBH * SQ * DD;   // 8,388,608
    const size_t lFloats   = (size_t)2 * NBH * SQ;        // 131,072
    const size_t needBytes = (accFloats + lFloats) * sizeof(float);

    if (ws_size >= needBytes) {
        float* wsAcc = (float*)d_ws;
        float* wsL   = wsAcc + accFloats;
        attn_fa<true><<<dim3(32 * 16 * 2), dim3(256), 0, stream>>>(Q, K, V, mask, Out, wsAcc, wsL);
        attn_combine<<<dim3((NBH * SQ * (DD / 4)) / 256), dim3(256), 0, stream>>>(wsAcc, wsL, Out);
    } else {
        attn_fa<false><<<dim3(32 * 16), dim3(256), 0, stream>>>(Q, K, V, mask, Out, nullptr, nullptr);
    }
}

// Round 5
// 313.821 us; speedup vs baseline: 1.3383x; 1.3383x over previous
//
#include <hip/hip_runtime.h>

#define SQ   2048
#define DD   64
#define BK   64
#define BQ   128
#define LDW  72
#define NBH  32

typedef _Float16 f16x8 __attribute__((ext_vector_type(8)));
typedef _Float16 f16x4 __attribute__((ext_vector_type(4)));
typedef float    f32x4 __attribute__((ext_vector_type(4)));

// scale = 1/sqrt(2048) (dk = key len!) folded with log2(e): exp(x*s) = 2^(x*s*log2e)
#define SCALE_LOG2E ((float)(0.02209708691207961 * 1.4426950408889634))
#define MASKED_VAL  (-1e10f * SCALE_LOG2E)

// NOTE: (256,4) forced VGPR->64 and spilled 1.4 GB to scratch (R4: 335us).
// (256,3) caps ~168; body needs ~104 -> 4 waves/SIMD fit with no spill.
template<bool SPLIT>
__global__ __launch_bounds__(256, 3)
void attn_fa(const float* __restrict__ Qg,
             const float* __restrict__ Kg,
             const float* __restrict__ Vg,
             const unsigned char* __restrict__ maskg,
             float* __restrict__ Og,
             float* __restrict__ wsAcc,
             float* __restrict__ wsL)
{
    __shared__ _Float16 Kl[2][BK * LDW];   // [buf][key][d]
    __shared__ _Float16 Vt[2][DD * LDW];   // [buf][d][key'] (frag-major permuted)

    const int tid  = threadIdx.x;
    const int lane = tid & 63;
    const int w    = tid >> 6;
    const int quad = lane >> 4;
    const int l16  = lane & 15;

    // XCD swizzle: low 5 bits = bh -> all q-tiles (and kv-halves) of one head on one XCD
    const int n    = blockIdx.x;
    const int bh   = (n & 7) + 8 * ((n >> 3) & 3);
    const int half = SPLIT ? ((n >> 5) & 1) : 0;
    const int qtile = SPLIT ? (n >> 6) : (n >> 5);
    const int qBase = qtile * BQ;
    const int kt0  = SPLIT ? half * 16 : 0;
    const int KTN  = SPLIT ? 16 : 32;

    // ---- Q fragments, pre-scaled by scale*log2e ----
    f16x8 qf[2][2];
#pragma unroll
    for (int qg = 0; qg < 2; ++qg) {
        const float* qrow = Qg + ((size_t)bh * SQ + qBase + w * 32 + qg * 16 + l16) * DD;
#pragma unroll
        for (int h = 0; h < 2; ++h) {
            float4 a = *(const float4*)(qrow + h * 32 + quad * 8);
            float4 b = *(const float4*)(qrow + h * 32 + quad * 8 + 4);
            qf[qg][h][0] = (_Float16)(a.x * SCALE_LOG2E); qf[qg][h][1] = (_Float16)(a.y * SCALE_LOG2E);
            qf[qg][h][2] = (_Float16)(a.z * SCALE_LOG2E); qf[qg][h][3] = (_Float16)(a.w * SCALE_LOG2E);
            qf[qg][h][4] = (_Float16)(b.x * SCALE_LOG2E); qf[qg][h][5] = (_Float16)(b.y * SCALE_LOG2E);
            qf[qg][h][6] = (_Float16)(b.z * SCALE_LOG2E); qf[qg][h][7] = (_Float16)(b.w * SCALE_LOG2E);
        }
    }

    f32x4 acc[2][4];
#pragma unroll
    for (int qg = 0; qg < 2; ++qg)
#pragma unroll
        for (int d = 0; d < 4; ++d) acc[qg][d] = (f32x4){0.f, 0.f, 0.f, 0.f};
    float lsum[2] = {0.f, 0.f};

    // staging maps
    const int sr  = tid >> 2;             // K row 0..63
    const int sc4 = (tid & 3) * 16;       // K col chunk
    const int vq  = tid & 15;             // V key-quad (keys vq*4..vq*4+3)
    const int vdb = (tid >> 4) * 4;       // V d block
    const int ctw = vq >> 2, qdw = vq & 3;
    const int keyp = (ctw >> 1) * 32 + qdw * 8 + (ctw & 1) * 4;  // permuted col'

    const float* Kbase = Kg + (size_t)bh * SQ * DD;
    const float* Vbase = Vg + (size_t)bh * SQ * DD;
    const unsigned char* mbase = maskg + (size_t)(qBase + (tid >> 1)) * SQ + (tid & 1) * 32;

    // ---- prologue: stage tile kt0 ----
    {
        const float* ks = Kbase + (size_t)(kt0 * BK + sr) * DD + sc4;
        float4 k0v = *(const float4*)(ks + 0), k1v = *(const float4*)(ks + 4);
        float4 k2v = *(const float4*)(ks + 8), k3v = *(const float4*)(ks + 12);
        const float* vb = Vbase + (size_t)(kt0 * BK + vq * 4) * DD + vdb;
        float4 v0 = *(const float4*)(vb);          float4 v1 = *(const float4*)(vb + DD);
        float4 v2 = *(const float4*)(vb + 2 * DD); float4 v3 = *(const float4*)(vb + 3 * DD);
        f16x8 y0, y1;
        y0[0]=(_Float16)k0v.x; y0[1]=(_Float16)k0v.y; y0[2]=(_Float16)k0v.z; y0[3]=(_Float16)k0v.w;
        y0[4]=(_Float16)k1v.x; y0[5]=(_Float16)k1v.y; y0[6]=(_Float16)k1v.z; y0[7]=(_Float16)k1v.w;
        y1[0]=(_Float16)k2v.x; y1[1]=(_Float16)k2v.y; y1[2]=(_Float16)k2v.z; y1[3]=(_Float16)k2v.w;
        y1[4]=(_Float16)k3v.x; y1[5]=(_Float16)k3v.y; y1[6]=(_Float16)k3v.z; y1[7]=(_Float16)k3v.w;
        *(f16x8*)&Kl[0][sr * LDW + sc4]     = y0;
        *(f16x8*)&Kl[0][sr * LDW + sc4 + 8] = y1;
        f16x4 t0 = {(_Float16)v0.x,(_Float16)v1.x,(_Float16)v2.x,(_Float16)v3.x};
        f16x4 t1 = {(_Float16)v0.y,(_Float16)v1.y,(_Float16)v2.y,(_Float16)v3.y};
        f16x4 t2 = {(_Float16)v0.z,(_Float16)v1.z,(_Float16)v2.z,(_Float16)v3.z};
        f16x4 t3 = {(_Float16)v0.w,(_Float16)v1.w,(_Float16)v2.w,(_Float16)v3.w};
        *(f16x4*)&Vt[0][(vdb + 0) * LDW + keyp] = t0;
        *(f16x4*)&Vt[0][(vdb + 1) * LDW + keyp] = t1;
        *(f16x4*)&Vt[0][(vdb + 2) * LDW + keyp] = t2;
        *(f16x4*)&Vt[0][(vdb + 3) * LDW + keyp] = t3;
    }
    uint4 ma = *(const uint4*)(mbase + kt0 * BK), mb = *(const uint4*)(mbase + kt0 * BK + 16);
    int tm = __syncthreads_or((int)(ma.x | ma.y | ma.z | ma.w | mb.x | mb.y | mb.z | mb.w));

#pragma unroll 2
    for (int idx = 0; idx < KTN; ++idx) {
        const int kt  = kt0 + idx;
        const int cur = idx & 1;
        const bool more = (idx + 1 < KTN);

        // ---- register prefetch of next tile ----
        float4 kx[4], vx[4]; uint4 ma2 = {0,0,0,0}, mb2 = {0,0,0,0};
        if (more) {
            const int k0n = (kt + 1) * BK;
            const float* ks = Kbase + (size_t)(k0n + sr) * DD + sc4;
            kx[0] = *(const float4*)(ks + 0);  kx[1] = *(const float4*)(ks + 4);
            kx[2] = *(const float4*)(ks + 8);  kx[3] = *(const float4*)(ks + 12);
            const float* vb = Vbase + (size_t)(k0n + vq * 4) * DD + vdb;
            vx[0] = *(const float4*)(vb);           vx[1] = *(const float4*)(vb + DD);
            vx[2] = *(const float4*)(vb + 2 * DD);  vx[3] = *(const float4*)(vb + 3 * DD);
            ma2 = *(const uint4*)(mbase + k0n);
            mb2 = *(const uint4*)(mbase + k0n + 16);
        }

        // ---- S^T = K*Q^T ----
        f32x4 sA[4], sB[4];
#pragma unroll
        for (int ct = 0; ct < 4; ++ct) {
            f16x8 kf0 = *(const f16x8*)&Kl[cur][(ct * 16 + l16) * LDW + quad * 8];
            f16x8 kf1 = *(const f16x8*)&Kl[cur][(ct * 16 + l16) * LDW + 32 + quad * 8];
            f32x4 c0 = (f32x4){0.f, 0.f, 0.f, 0.f};
            c0 = __builtin_amdgcn_mfma_f32_16x16x32_f16(kf0, qf[0][0], c0, 0, 0, 0);
            c0 = __builtin_amdgcn_mfma_f32_16x16x32_f16(kf1, qf[0][1], c0, 0, 0, 0);
            sA[ct] = c0;
            f32x4 c1 = (f32x4){0.f, 0.f, 0.f, 0.f};
            c1 = __builtin_amdgcn_mfma_f32_16x16x32_f16(kf0, qf[1][0], c1, 0, 0, 0);
            c1 = __builtin_amdgcn_mfma_f32_16x16x32_f16(kf1, qf[1][1], c1, 0, 0, 0);
            sB[ct] = c1;
        }

        // ---- mask (rare slow path; logits already in log2 domain) ----
        if (tm) {
#pragma unroll
            for (int qg = 0; qg < 2; ++qg) {
                const int qgq = qBase + w * 32 + qg * 16 + l16;
#pragma unroll
                for (int ct = 0; ct < 4; ++ct)
#pragma unroll
                    for (int r = 0; r < 4; ++r) {
                        const int kg = kt * BK + ct * 16 + quad * 4 + r;
                        if (maskg[(size_t)qgq * SQ + kg]) {
                            if (qg == 0) sA[ct][r] = MASKED_VAL; else sB[ct][r] = MASKED_VAL;
                        }
                    }
            }
        }

        // ---- softmax numerators: per-lane, no max (|logit| bounded), raw v_exp ----
        f16x8 pA[2], pB[2];   // [kb]: 8 keys = ct(2kb) r0..3 | ct(2kb+1) r0..3
        float ls0 = 0.f, ls1 = 0.f;
#pragma unroll
        for (int kb = 0; kb < 2; ++kb)
#pragma unroll
            for (int j = 0; j < 8; ++j) {
                const int ct = kb * 2 + (j >> 2), r = j & 3;
                const float ea = __builtin_amdgcn_exp2f(sA[ct][r]);
                const float eb = __builtin_amdgcn_exp2f(sB[ct][r]);
                ls0 += ea; ls1 += eb;
                pA[kb][j] = (_Float16)ea;
                pB[kb][j] = (_Float16)eb;
            }
        lsum[0] += ls0; lsum[1] += ls1;

        // ---- P*V with 16x16x32: B-frag = one contiguous f16x8 from permuted Vt ----
#pragma unroll
        for (int dt = 0; dt < 4; ++dt)
#pragma unroll
            for (int kb = 0; kb < 2; ++kb) {
                f16x8 vv = *(const f16x8*)&Vt[cur][(dt * 16 + l16) * LDW + kb * 32 + quad * 8];
                acc[0][dt] = __builtin_amdgcn_mfma_f32_16x16x32_f16(pA[kb], vv, acc[0][dt], 0, 0, 0);
                acc[1][dt] = __builtin_amdgcn_mfma_f32_16x16x32_f16(pB[kb], vv, acc[1][dt], 0, 0, 0);
            }

        // ---- stage prefetched tile ----
        if (more) {
            f16x8 y0, y1;
            y0[0]=(_Float16)kx[0].x; y0[1]=(_Float16)kx[0].y; y0[2]=(_Float16)kx[0].z; y0[3]=(_Float16)kx[0].w;
            y0[4]=(_Float16)kx[1].x; y0[5]=(_Float16)kx[1].y; y0[6]=(_Float16)kx[1].z; y0[7]=(_Float16)kx[1].w;
            y1[0]=(_Float16)kx[2].x; y1[1]=(_Float16)kx[2].y; y1[2]=(_Float16)kx[2].z; y1[3]=(_Float16)kx[2].w;
            y1[4]=(_Float16)kx[3].x; y1[5]=(_Float16)kx[3].y; y1[6]=(_Float16)kx[3].z; y1[7]=(_Float16)kx[3].w;
            *(f16x8*)&Kl[cur ^ 1][sr * LDW + sc4]     = y0;
            *(f16x8*)&Kl[cur ^ 1][sr * LDW + sc4 + 8] = y1;
            f16x4 t0 = {(_Float16)vx[0].x,(_Float16)vx[1].x,(_Float16)vx[2].x,(_Float16)vx[3].x};
            f16x4 t1 = {(_Float16)vx[0].y,(_Float16)vx[1].y,(_Float16)vx[2].y,(_Float16)vx[3].y};
            f16x4 t2 = {(_Float16)vx[0].z,(_Float16)vx[1].z,(_Float16)vx[2].z,(_Float16)vx[3].z};
            f16x4 t3 = {(_Float16)vx[0].w,(_Float16)vx[1].w,(_Float16)vx[2].w,(_Float16)vx[3].w};
            *(f16x4*)&Vt[cur ^ 1][(vdb + 0) * LDW + keyp] = t0;
            *(f16x4*)&Vt[cur ^ 1][(vdb + 1) * LDW + keyp] = t1;
            *(f16x4*)&Vt[cur ^ 1][(vdb + 2) * LDW + keyp] = t2;
            *(f16x4*)&Vt[cur ^ 1][(vdb + 3) * LDW + keyp] = t3;
        }
        tm = __syncthreads_or((int)(ma2.x | ma2.y | ma2.z | ma2.w | mb2.x | mb2.y | mb2.z | mb2.w));
    }

    // ---- epilogue ----
#pragma unroll
    for (int qg = 0; qg < 2; ++qg) {
        float l = lsum[qg];
        l += __shfl_xor(l, 16);
        l += __shfl_xor(l, 32);
        if (SPLIT) {
            float* ob = wsAcc + (((size_t)half * NBH + bh) * SQ + qBase + w * 32 + qg * 16) * DD;
#pragma unroll
            for (int r = 0; r < 4; ++r) {
                const int qr = quad * 4 + r;
#pragma unroll
                for (int dt = 0; dt < 4; ++dt)
                    ob[qr * DD + dt * 16 + l16] = acc[qg][dt][r];
            }
            if (quad == 0)
                wsL[((size_t)half * NBH + bh) * SQ + qBase + w * 32 + qg * 16 + l16] = l;
        } else {
            float lrow[4];
#pragma unroll
            for (int r = 0; r < 4; ++r) lrow[r] = __shfl(l, quad * 4 + r);
            float* ob = Og + ((size_t)bh * SQ + qBase + w * 32 + qg * 16) * DD;
#pragma unroll
            for (int r = 0; r < 4; ++r) {
                const float inv = 1.0f / lrow[r];
                const int qr = quad * 4 + r;
#pragma unroll
                for (int dt = 0; dt < 4; ++dt)
                    ob[qr * DD + dt * 16 + l16] = acc[qg][dt][r] * inv;
            }
        }
    }
}

__global__ __launch_bounds__(256)
void attn_combine(const float* __restrict__ wsAcc,
                  const float* __restrict__ wsL,
                  float* __restrict__ Og)
{
    const int G   = blockIdx.x * 256 + threadIdx.x;   // 0 .. 32*2048*16-1
    const int row = G >> 4;                            // bh*SQ + q
    const int c   = G & 15;
    const size_t HALF4 = (size_t)NBH * SQ * (DD / 4);
    float4 a0 = ((const float4*)wsAcc)[(size_t)row * 16 + c];
    float4 a1 = ((const float4*)wsAcc)[HALF4 + (size_t)row * 16 + c];
    const float inv = 1.0f / (wsL[row] + wsL[(size_t)NBH * SQ + row]);
    float4 o;
    o.x = (a0.x + a1.x) * inv;
    o.y = (a0.y + a1.y) * inv;
    o.z = (a0.z + a1.z) * inv;
    o.w = (a0.w + a1.w) * inv;
    ((float4*)Og)[(size_t)row * 16 + c] = o;
}

extern "C" void kernel_launch(void* const* d_in, const int* in_sizes, int n_in,
                              void* d_out, int out_size, void* d_ws, size_t ws_size,
                              hipStream_t stream) {
    const float* Q = (const float*)d_in[0];
    const float* K = (const float*)d_in[1];
    const float* V = (const float*)d_in[2];
    const unsigned char* mask = (const unsigned char*)d_in[3];
    float* Out = (float*)d_out;

    const size_t accFloats = (size_t)2 * NBH * SQ * DD;   // 8,388,608
    const size_t lFloats   = (size_t)2 * NBH * SQ;        // 131,072
    const size_t needBytes = (accFloats + lFloats) * sizeof(float);

    if (ws_size >= needBytes) {
        float* wsAcc = (float*)d_ws;
        float* wsL   = wsAcc + accFloats;
        attn_fa<true><<<dim3(32 * 16 * 2), dim3(256), 0, stream>>>(Q, K, V, mask, Out, wsAcc, wsL);
        attn_combine<<<dim3((NBH * SQ * (DD / 4)) / 256), dim3(256), 0, stream>>>(wsAcc, wsL, Out);
    } else {
        attn_fa<false><<<dim3(32 * 16), dim3(256), 0, stream>>>(Q, K, V, mask, Out, nullptr, nullptr);
    }
}

// Round 6
// 169.480 us; speedup vs baseline: 2.4780x; 1.8517x over previous
//
#include <hip/hip_runtime.h>

#define SQ   2048
#define DD   64
#define BK   64
#define BQ   128
#define LDW  72
#define NBH  32

typedef _Float16 f16x8 __attribute__((ext_vector_type(8)));
typedef _Float16 f16x4 __attribute__((ext_vector_type(4)));
typedef float    f32x4 __attribute__((ext_vector_type(4)));

// scale = 1/sqrt(2048) (dk = key len!) folded with log2(e): exp(x*s) = 2^(x*s*log2e)
#define SCALE_LOG2E ((float)(0.02209708691207961 * 1.4426950408889634))
#define MASKED_VAL  (-1e10f * SCALE_LOG2E)

// Register-pressure history: (256,4) -> 64 VGPR, 1.4 GB spill (R4, 335us).
// (256,3) -> 84 VGPR, 620 MB spill (R5, 233us). (256,2) -> 104 VGPR, NO spill
// (R3, 87us at grid 512). 104 VGPR <= 128 already allows 4 waves/SIMD in HW,
// and LDS 37.4 KB allows 4 blocks/CU -- so with grid 1024 (split-KV) we get
// 4 blocks/CU without constraining the allocator. Do NOT raise min-waves.
template<bool SPLIT>
__global__ __launch_bounds__(256, 2)
void attn_fa(const float* __restrict__ Qg,
             const float* __restrict__ Kg,
             const float* __restrict__ Vg,
             const unsigned char* __restrict__ maskg,
             float* __restrict__ Og,
             float* __restrict__ wsAcc,
             float* __restrict__ wsL)
{
    __shared__ _Float16 Kl[2][BK * LDW];   // [buf][key][d]
    __shared__ _Float16 Vt[2][DD * LDW];   // [buf][d][key'] (frag-major permuted)

    const int tid  = threadIdx.x;
    const int lane = tid & 63;
    const int w    = tid >> 6;
    const int quad = lane >> 4;
    const int l16  = lane & 15;

    // XCD swizzle: low 5 bits = bh -> all q-tiles (and kv-halves) of one head on one XCD
    const int n    = blockIdx.x;
    const int bh   = (n & 7) + 8 * ((n >> 3) & 3);
    const int half = SPLIT ? ((n >> 5) & 1) : 0;
    const int qtile = SPLIT ? (n >> 6) : (n >> 5);
    const int qBase = qtile * BQ;
    const int kt0  = SPLIT ? half * 16 : 0;
    const int KTN  = SPLIT ? 16 : 32;

    // ---- Q fragments, pre-scaled by scale*log2e ----
    f16x8 qf[2][2];
#pragma unroll
    for (int qg = 0; qg < 2; ++qg) {
        const float* qrow = Qg + ((size_t)bh * SQ + qBase + w * 32 + qg * 16 + l16) * DD;
#pragma unroll
        for (int h = 0; h < 2; ++h) {
            float4 a = *(const float4*)(qrow + h * 32 + quad * 8);
            float4 b = *(const float4*)(qrow + h * 32 + quad * 8 + 4);
            qf[qg][h][0] = (_Float16)(a.x * SCALE_LOG2E); qf[qg][h][1] = (_Float16)(a.y * SCALE_LOG2E);
            qf[qg][h][2] = (_Float16)(a.z * SCALE_LOG2E); qf[qg][h][3] = (_Float16)(a.w * SCALE_LOG2E);
            qf[qg][h][4] = (_Float16)(b.x * SCALE_LOG2E); qf[qg][h][5] = (_Float16)(b.y * SCALE_LOG2E);
            qf[qg][h][6] = (_Float16)(b.z * SCALE_LOG2E); qf[qg][h][7] = (_Float16)(b.w * SCALE_LOG2E);
        }
    }

    f32x4 acc[2][4];
#pragma unroll
    for (int qg = 0; qg < 2; ++qg)
#pragma unroll
        for (int d = 0; d < 4; ++d) acc[qg][d] = (f32x4){0.f, 0.f, 0.f, 0.f};
    float lsum[2] = {0.f, 0.f};

    // staging maps
    const int sr  = tid >> 2;             // K row 0..63
    const int sc4 = (tid & 3) * 16;       // K col chunk
    const int vq  = tid & 15;             // V key-quad (keys vq*4..vq*4+3)
    const int vdb = (tid >> 4) * 4;       // V d block
    const int ctw = vq >> 2, qdw = vq & 3;
    const int keyp = (ctw >> 1) * 32 + qdw * 8 + (ctw & 1) * 4;  // permuted col'

    const float* Kbase = Kg + (size_t)bh * SQ * DD;
    const float* Vbase = Vg + (size_t)bh * SQ * DD;
    const unsigned char* mbase = maskg + (size_t)(qBase + (tid >> 1)) * SQ + (tid & 1) * 32;

    // ---- prologue: stage tile kt0 ----
    {
        const float* ks = Kbase + (size_t)(kt0 * BK + sr) * DD + sc4;
        float4 k0v = *(const float4*)(ks + 0), k1v = *(const float4*)(ks + 4);
        float4 k2v = *(const float4*)(ks + 8), k3v = *(const float4*)(ks + 12);
        const float* vb = Vbase + (size_t)(kt0 * BK + vq * 4) * DD + vdb;
        float4 v0 = *(const float4*)(vb);          float4 v1 = *(const float4*)(vb + DD);
        float4 v2 = *(const float4*)(vb + 2 * DD); float4 v3 = *(const float4*)(vb + 3 * DD);
        f16x8 y0, y1;
        y0[0]=(_Float16)k0v.x; y0[1]=(_Float16)k0v.y; y0[2]=(_Float16)k0v.z; y0[3]=(_Float16)k0v.w;
        y0[4]=(_Float16)k1v.x; y0[5]=(_Float16)k1v.y; y0[6]=(_Float16)k1v.z; y0[7]=(_Float16)k1v.w;
        y1[0]=(_Float16)k2v.x; y1[1]=(_Float16)k2v.y; y1[2]=(_Float16)k2v.z; y1[3]=(_Float16)k2v.w;
        y1[4]=(_Float16)k3v.x; y1[5]=(_Float16)k3v.y; y1[6]=(_Float16)k3v.z; y1[7]=(_Float16)k3v.w;
        *(f16x8*)&Kl[0][sr * LDW + sc4]     = y0;
        *(f16x8*)&Kl[0][sr * LDW + sc4 + 8] = y1;
        f16x4 t0 = {(_Float16)v0.x,(_Float16)v1.x,(_Float16)v2.x,(_Float16)v3.x};
        f16x4 t1 = {(_Float16)v0.y,(_Float16)v1.y,(_Float16)v2.y,(_Float16)v3.y};
        f16x4 t2 = {(_Float16)v0.z,(_Float16)v1.z,(_Float16)v2.z,(_Float16)v3.z};
        f16x4 t3 = {(_Float16)v0.w,(_Float16)v1.w,(_Float16)v2.w,(_Float16)v3.w};
        *(f16x4*)&Vt[0][(vdb + 0) * LDW + keyp] = t0;
        *(f16x4*)&Vt[0][(vdb + 1) * LDW + keyp] = t1;
        *(f16x4*)&Vt[0][(vdb + 2) * LDW + keyp] = t2;
        *(f16x4*)&Vt[0][(vdb + 3) * LDW + keyp] = t3;
    }
    uint4 ma = *(const uint4*)(mbase + kt0 * BK), mb = *(const uint4*)(mbase + kt0 * BK + 16);
    int tm = __syncthreads_or((int)(ma.x | ma.y | ma.z | ma.w | mb.x | mb.y | mb.z | mb.w));

#pragma unroll 2
    for (int idx = 0; idx < KTN; ++idx) {
        const int kt  = kt0 + idx;
        const int cur = idx & 1;
        const bool more = (idx + 1 < KTN);

        // ---- register prefetch of next tile ----
        float4 kx[4], vx[4]; uint4 ma2 = {0,0,0,0}, mb2 = {0,0,0,0};
        if (more) {
            const int k0n = (kt + 1) * BK;
            const float* ks = Kbase + (size_t)(k0n + sr) * DD + sc4;
            kx[0] = *(const float4*)(ks + 0);  kx[1] = *(const float4*)(ks + 4);
            kx[2] = *(const float4*)(ks + 8);  kx[3] = *(const float4*)(ks + 12);
            const float* vb = Vbase + (size_t)(k0n + vq * 4) * DD + vdb;
            vx[0] = *(const float4*)(vb);           vx[1] = *(const float4*)(vb + DD);
            vx[2] = *(const float4*)(vb + 2 * DD);  vx[3] = *(const float4*)(vb + 3 * DD);
            ma2 = *(const uint4*)(mbase + k0n);
            mb2 = *(const uint4*)(mbase + k0n + 16);
        }

        // ---- S^T = K*Q^T ----
        f32x4 sA[4], sB[4];
#pragma unroll
        for (int ct = 0; ct < 4; ++ct) {
            f16x8 kf0 = *(const f16x8*)&Kl[cur][(ct * 16 + l16) * LDW + quad * 8];
            f16x8 kf1 = *(const f16x8*)&Kl[cur][(ct * 16 + l16) * LDW + 32 + quad * 8];
            f32x4 c0 = (f32x4){0.f, 0.f, 0.f, 0.f};
            c0 = __builtin_amdgcn_mfma_f32_16x16x32_f16(kf0, qf[0][0], c0, 0, 0, 0);
            c0 = __builtin_amdgcn_mfma_f32_16x16x32_f16(kf1, qf[0][1], c0, 0, 0, 0);
            sA[ct] = c0;
            f32x4 c1 = (f32x4){0.f, 0.f, 0.f, 0.f};
            c1 = __builtin_amdgcn_mfma_f32_16x16x32_f16(kf0, qf[1][0], c1, 0, 0, 0);
            c1 = __builtin_amdgcn_mfma_f32_16x16x32_f16(kf1, qf[1][1], c1, 0, 0, 0);
            sB[ct] = c1;
        }

        // ---- mask (rare slow path; logits already in log2 domain) ----
        if (tm) {
#pragma unroll
            for (int qg = 0; qg < 2; ++qg) {
                const int qgq = qBase + w * 32 + qg * 16 + l16;
#pragma unroll
                for (int ct = 0; ct < 4; ++ct)
#pragma unroll
                    for (int r = 0; r < 4; ++r) {
                        const int kg = kt * BK + ct * 16 + quad * 4 + r;
                        if (maskg[(size_t)qgq * SQ + kg]) {
                            if (qg == 0) sA[ct][r] = MASKED_VAL; else sB[ct][r] = MASKED_VAL;
                        }
                    }
            }
        }

        // ---- softmax numerators: per-lane, no max (|logit| bounded), raw v_exp ----
        f16x8 pA[2], pB[2];   // [kb]: 8 keys = ct(2kb) r0..3 | ct(2kb+1) r0..3
        float ls0 = 0.f, ls1 = 0.f;
#pragma unroll
        for (int kb = 0; kb < 2; ++kb)
#pragma unroll
            for (int j = 0; j < 8; ++j) {
                const int ct = kb * 2 + (j >> 2), r = j & 3;
                const float ea = __builtin_amdgcn_exp2f(sA[ct][r]);
                const float eb = __builtin_amdgcn_exp2f(sB[ct][r]);
                ls0 += ea; ls1 += eb;
                pA[kb][j] = (_Float16)ea;
                pB[kb][j] = (_Float16)eb;
            }
        lsum[0] += ls0; lsum[1] += ls1;

        // ---- P*V with 16x16x32: B-frag = one contiguous f16x8 from permuted Vt ----
#pragma unroll
        for (int dt = 0; dt < 4; ++dt)
#pragma unroll
            for (int kb = 0; kb < 2; ++kb) {
                f16x8 vv = *(const f16x8*)&Vt[cur][(dt * 16 + l16) * LDW + kb * 32 + quad * 8];
                acc[0][dt] = __builtin_amdgcn_mfma_f32_16x16x32_f16(pA[kb], vv, acc[0][dt], 0, 0, 0);
                acc[1][dt] = __builtin_amdgcn_mfma_f32_16x16x32_f16(pB[kb], vv, acc[1][dt], 0, 0, 0);
            }

        // ---- stage prefetched tile ----
        if (more) {
            f16x8 y0, y1;
            y0[0]=(_Float16)kx[0].x; y0[1]=(_Float16)kx[0].y; y0[2]=(_Float16)kx[0].z; y0[3]=(_Float16)kx[0].w;
            y0[4]=(_Float16)kx[1].x; y0[5]=(_Float16)kx[1].y; y0[6]=(_Float16)kx[1].z; y0[7]=(_Float16)kx[1].w;
            y1[0]=(_Float16)kx[2].x; y1[1]=(_Float16)kx[2].y; y1[2]=(_Float16)kx[2].z; y1[3]=(_Float16)kx[2].w;
            y1[4]=(_Float16)kx[3].x; y1[5]=(_Float16)kx[3].y; y1[6]=(_Float16)kx[3].z; y1[7]=(_Float16)kx[3].w;
            *(f16x8*)&Kl[cur ^ 1][sr * LDW + sc4]     = y0;
            *(f16x8*)&Kl[cur ^ 1][sr * LDW + sc4 + 8] = y1;
            f16x4 t0 = {(_Float16)vx[0].x,(_Float16)vx[1].x,(_Float16)vx[2].x,(_Float16)vx[3].x};
            f16x4 t1 = {(_Float16)vx[0].y,(_Float16)vx[1].y,(_Float16)vx[2].y,(_Float16)vx[3].y};
            f16x4 t2 = {(_Float16)vx[0].z,(_Float16)vx[1].z,(_Float16)vx[2].z,(_Float16)vx[3].z};
            f16x4 t3 = {(_Float16)vx[0].w,(_Float16)vx[1].w,(_Float16)vx[2].w,(_Float16)vx[3].w};
            *(f16x4*)&Vt[cur ^ 1][(vdb + 0) * LDW + keyp] = t0;
            *(f16x4*)&Vt[cur ^ 1][(vdb + 1) * LDW + keyp] = t1;
            *(f16x4*)&Vt[cur ^ 1][(vdb + 2) * LDW + keyp] = t2;
            *(f16x4*)&Vt[cur ^ 1][(vdb + 3) * LDW + keyp] = t3;
        }
        tm = __syncthreads_or((int)(ma2.x | ma2.y | ma2.z | ma2.w | mb2.x | mb2.y | mb2.z | mb2.w));
    }

    // ---- epilogue ----
#pragma unroll
    for (int qg = 0; qg < 2; ++qg) {
        float l = lsum[qg];
        l += __shfl_xor(l, 16);
        l += __shfl_xor(l, 32);
        if (SPLIT) {
            float* ob = wsAcc + (((size_t)half * NBH + bh) * SQ + qBase + w * 32 + qg * 16) * DD;
#pragma unroll
            for (int r = 0; r < 4; ++r) {
                const int qr = quad * 4 + r;
#pragma unroll
                for (int dt = 0; dt < 4; ++dt)
                    ob[qr * DD + dt * 16 + l16] = acc[qg][dt][r];
            }
            if (quad == 0)
                wsL[((size_t)half * NBH + bh) * SQ + qBase + w * 32 + qg * 16 + l16] = l;
        } else {
            float lrow[4];
#pragma unroll
            for (int r = 0; r < 4; ++r) lrow[r] = __shfl(l, quad * 4 + r);
            float* ob = Og + ((size_t)bh * SQ + qBase + w * 32 + qg * 16) * DD;
#pragma unroll
            for (int r = 0; r < 4; ++r) {
                const float inv = 1.0f / lrow[r];
                const int qr = quad * 4 + r;
#pragma unroll
                for (int dt = 0; dt < 4; ++dt)
                    ob[qr * DD + dt * 16 + l16] = acc[qg][dt][r] * inv;
            }
        }
    }
}

__global__ __launch_bounds__(256)
void attn_combine(const float* __restrict__ wsAcc,
                  const float* __restrict__ wsL,
                  float* __restrict__ Og)
{
    const int G   = blockIdx.x * 256 + threadIdx.x;   // 0 .. 32*2048*16-1
    const int row = G >> 4;                            // bh*SQ + q
    const int c   = G & 15;
    const size_t HALF4 = (size_t)NBH * SQ * (DD / 4);
    float4 a0 = ((const float4*)wsAcc)[(size_t)row * 16 + c];
    float4 a1 = ((const float4*)wsAcc)[HALF4 + (size_t)row * 16 + c];
    const float inv = 1.0f / (wsL[row] + wsL[(size_t)NBH * SQ + row]);
    float4 o;
    o.x = (a0.x + a1.x) * inv;
    o.y = (a0.y + a1.y) * inv;
    o.z = (a0.z + a1.z) * inv;
    o.w = (a0.w + a1.w) * inv;
    ((float4*)Og)[(size_t)row * 16 + c] = o;
}

extern "C" void kernel_launch(void* const* d_in, const int* in_sizes, int n_in,
                              void* d_out, int out_size, void* d_ws, size_t ws_size,
                              hipStream_t stream) {
    const float* Q = (const float*)d_in[0];
    const float* K = (const float*)d_in[1];
    const float* V = (const float*)d_in[2];
    const unsigned char* mask = (const unsigned char*)d_in[3];
    float* Out = (float*)d_out;

    const size_t accFloats = (size_t)2 * NBH * SQ * DD;   // 8,388,608
    const size_t lFloats   = (size_t)2 * NBH * SQ;        // 131,072
    const size_t needBytes = (accFloats + lFloats) * sizeof(float);

    if (ws_size >= needBytes) {
        float* wsAcc = (float*)d_ws;
        float* wsL   = wsAcc + accFloats;
        attn_fa<true><<<dim3(32 * 16 * 2), dim3(256), 0, stream>>>(Q, K, V, mask, Out, wsAcc, wsL);
        attn_combine<<<dim3((NBH * SQ * (DD / 4)) / 256), dim3(256), 0, stream>>>(wsAcc, wsL, Out);
    } else {
        attn_fa<false><<<dim3(32 * 16), dim3(256), 0, stream>>>(Q, K, V, mask, Out, nullptr, nullptr);
    }
}